// Round 2
// baseline (60.946 us; speedup 1.0000x reference)
//
#include <hip/hip_runtime.h>

// loss = sum_{b,m,n} | dot(src[b,n,:], tgts[b,m,n,:]) |
// B=64, M=16, N=64, D=1024
//
// One wave per (b, n, m-half): src row loaded ONCE into 16 registers
// (4 x float4 per lane), then 8 tgts rows streamed against it.
// All VMEM issue bandwidth goes to the 256 MiB tgts stream.

__global__ __launch_bounds__(256) void orth_loss_kernel(
    const float* __restrict__ src,
    const float* __restrict__ tgts,
    float* __restrict__ out,
    int total_waves)   // B * 2 * N  (m split in halves of 8)
{
    const int wave = threadIdx.x >> 6;   // 0..3
    const int lane = threadIdx.x & 63;

    float local = 0.0f;

    for (int w = blockIdx.x * 4 + wave; w < total_waves; w += gridDim.x * 4) {
        const int n  = w & 63;          // N = 64
        const int t  = w >> 6;          // b*2 + mhalf
        const int mh = t & 1;
        const int b  = t >> 1;

        // src row -> registers (16 floats/lane, coalesced float4)
        const float4* __restrict__ sp =
            reinterpret_cast<const float4*>(src + ((size_t)(b * 64 + n)) * 1024);
        const float4 s0 = sp[lane];
        const float4 s1 = sp[lane + 64];
        const float4 s2 = sp[lane + 128];
        const float4 s3 = sp[lane + 192];

        // stream 8 tgts rows: tgts[b, mh*8 + mi, n, :]
        const size_t tbase = (((size_t)b * 16 + mh * 8) * 64 + n) * (size_t)1024;

#pragma unroll
        for (int mi = 0; mi < 8; ++mi) {
            const float4* __restrict__ tp =
                reinterpret_cast<const float4*>(tgts + tbase + (size_t)mi * 64 * 1024);
            const float4 t0 = tp[lane];
            const float4 t1 = tp[lane + 64];
            const float4 t2 = tp[lane + 128];
            const float4 t3 = tp[lane + 192];

            float dot = 0.0f;
            dot = fmaf(t0.x, s0.x, dot); dot = fmaf(t0.y, s0.y, dot);
            dot = fmaf(t0.z, s0.z, dot); dot = fmaf(t0.w, s0.w, dot);
            dot = fmaf(t1.x, s1.x, dot); dot = fmaf(t1.y, s1.y, dot);
            dot = fmaf(t1.z, s1.z, dot); dot = fmaf(t1.w, s1.w, dot);
            dot = fmaf(t2.x, s2.x, dot); dot = fmaf(t2.y, s2.y, dot);
            dot = fmaf(t2.z, s2.z, dot); dot = fmaf(t2.w, s2.w, dot);
            dot = fmaf(t3.x, s3.x, dot); dot = fmaf(t3.y, s3.y, dot);
            dot = fmaf(t3.z, s3.z, dot); dot = fmaf(t3.w, s3.w, dot);

            // 64-lane reduce
#pragma unroll
            for (int off = 32; off > 0; off >>= 1)
                dot += __shfl_down(dot, off, 64);

            if (lane == 0) local += fabsf(dot);
        }
    }

    __shared__ float sbuf[4];
    if (lane == 0) sbuf[wave] = local;
    __syncthreads();

    if (threadIdx.x == 0) {
        const float s = sbuf[0] + sbuf[1] + sbuf[2] + sbuf[3];
        atomicAdd(out, s);
    }
}

extern "C" void kernel_launch(void* const* d_in, const int* in_sizes, int n_in,
                              void* d_out, int out_size, void* d_ws, size_t ws_size,
                              hipStream_t stream) {
    const float* src  = (const float*)d_in[0];   // [B, N, D]
    const float* tgts = (const float*)d_in[1];   // [B, M, N, D]
    float* out = (float*)d_out;                  // [1]

    // B*M*N*D = in_sizes[1]; D=1024, M=16, N=64
    const int total_rows  = in_sizes[1] / 1024;  // B*M*N = 65536
    const int total_waves = total_rows / 8;      // one wave per 8 rows = 8192

    hipMemsetAsync(out, 0, sizeof(float), stream);

    const int blocks = 2048;   // 8192 waves / 4 per block
    orth_loss_kernel<<<blocks, 256, 0, stream>>>(src, tgts, out, total_waves);
}

// Round 3
// 59.954 us; speedup vs baseline: 1.0165x; 1.0165x over previous
//
#include <hip/hip_runtime.h>

// loss = sum_{b,m,n} | dot(src[b,n,:], tgts[b,m,n,:]) |
// B=64, M=16, N=64, D=1024
//
// One wave per (b, n): src row loaded ONCE into 16 registers, then all 16
// tgts rows streamed against it with a double-buffered prefetch (named A/B
// buffers, statically indexed) so ~4 KiB stays in flight per wave through
// the FMA + shuffle-reduce window. __launch_bounds__(256,4) caps VGPR at
// 128 so occupancy stays >= 4 waves/SIMD.

__global__ __launch_bounds__(256, 4) void orth_loss_kernel(
    const float* __restrict__ src,
    const float* __restrict__ tgts,
    float* __restrict__ out,
    int total_waves)   // B * N = 4096
{
    const int wave = threadIdx.x >> 6;   // 0..3
    const int lane = threadIdx.x & 63;

    float local = 0.0f;

    for (int w = blockIdx.x * 4 + wave; w < total_waves; w += gridDim.x * 4) {
        const int n = w & 63;           // N = 64
        const int b = w >> 6;

        // src row -> 16 registers (4 x float4 per lane, coalesced)
        const float4* __restrict__ sp =
            reinterpret_cast<const float4*>(src + ((size_t)(b * 64 + n)) * 1024);
        const float4 s0 = sp[lane];
        const float4 s1 = sp[lane + 64];
        const float4 s2 = sp[lane + 128];
        const float4 s3 = sp[lane + 192];

        // tgts rows: tgts[b, mi, n, :], mi = 0..15, stride 64*1024 floats
        const float* __restrict__ trow0 = tgts + (((size_t)b * 16) * 64 + n) * 1024;

        // preload row 0 into buffer A
        const float4* __restrict__ tp0 = reinterpret_cast<const float4*>(trow0);
        float4 a0 = tp0[lane];
        float4 a1 = tp0[lane + 64];
        float4 a2 = tp0[lane + 128];
        float4 a3 = tp0[lane + 192];
        float4 b0, b1, b2, b3;

#pragma unroll
        for (int mi = 0; mi < 16; mi += 2) {
            // prefetch row mi+1 into B
            {
                const float4* __restrict__ tpb =
                    reinterpret_cast<const float4*>(trow0 + (size_t)(mi + 1) * 64 * 1024);
                b0 = tpb[lane];
                b1 = tpb[lane + 64];
                b2 = tpb[lane + 128];
                b3 = tpb[lane + 192];
            }
            // compute with A (row mi)
            {
                float dot = 0.0f;
                dot = fmaf(a0.x, s0.x, dot); dot = fmaf(a0.y, s0.y, dot);
                dot = fmaf(a0.z, s0.z, dot); dot = fmaf(a0.w, s0.w, dot);
                dot = fmaf(a1.x, s1.x, dot); dot = fmaf(a1.y, s1.y, dot);
                dot = fmaf(a1.z, s1.z, dot); dot = fmaf(a1.w, s1.w, dot);
                dot = fmaf(a2.x, s2.x, dot); dot = fmaf(a2.y, s2.y, dot);
                dot = fmaf(a2.z, s2.z, dot); dot = fmaf(a2.w, s2.w, dot);
                dot = fmaf(a3.x, s3.x, dot); dot = fmaf(a3.y, s3.y, dot);
                dot = fmaf(a3.z, s3.z, dot); dot = fmaf(a3.w, s3.w, dot);
#pragma unroll
                for (int off = 32; off > 0; off >>= 1)
                    dot += __shfl_down(dot, off, 64);
                if (lane == 0) local += fabsf(dot);
            }
            // prefetch row mi+2 into A (folds away on last iteration)
            if (mi + 2 < 16) {
                const float4* __restrict__ tpa =
                    reinterpret_cast<const float4*>(trow0 + (size_t)(mi + 2) * 64 * 1024);
                a0 = tpa[lane];
                a1 = tpa[lane + 64];
                a2 = tpa[lane + 128];
                a3 = tpa[lane + 192];
            }
            // compute with B (row mi+1)
            {
                float dot = 0.0f;
                dot = fmaf(b0.x, s0.x, dot); dot = fmaf(b0.y, s0.y, dot);
                dot = fmaf(b0.z, s0.z, dot); dot = fmaf(b0.w, s0.w, dot);
                dot = fmaf(b1.x, s1.x, dot); dot = fmaf(b1.y, s1.y, dot);
                dot = fmaf(b1.z, s1.z, dot); dot = fmaf(b1.w, s1.w, dot);
                dot = fmaf(b2.x, s2.x, dot); dot = fmaf(b2.y, s2.y, dot);
                dot = fmaf(b2.z, s2.z, dot); dot = fmaf(b2.w, s2.w, dot);
                dot = fmaf(b3.x, s3.x, dot); dot = fmaf(b3.y, s3.y, dot);
                dot = fmaf(b3.z, s3.z, dot); dot = fmaf(b3.w, s3.w, dot);
#pragma unroll
                for (int off = 32; off > 0; off >>= 1)
                    dot += __shfl_down(dot, off, 64);
                if (lane == 0) local += fabsf(dot);
            }
        }
    }

    __shared__ float sbuf[4];
    if (lane == 0) sbuf[wave] = local;
    __syncthreads();

    if (threadIdx.x == 0) {
        const float s = sbuf[0] + sbuf[1] + sbuf[2] + sbuf[3];
        atomicAdd(out, s);
    }
}

extern "C" void kernel_launch(void* const* d_in, const int* in_sizes, int n_in,
                              void* d_out, int out_size, void* d_ws, size_t ws_size,
                              hipStream_t stream) {
    const float* src  = (const float*)d_in[0];   // [B, N, D]
    const float* tgts = (const float*)d_in[1];   // [B, M, N, D]
    float* out = (float*)d_out;                  // [1]

    // B*N = src elements / D
    const int total_waves = in_sizes[0] / 1024;  // 4096

    hipMemsetAsync(out, 0, sizeof(float), stream);

    const int blocks = total_waves / 4;          // 1024 blocks x 4 waves
    orth_loss_kernel<<<blocks, 256, 0, stream>>>(src, tgts, out, total_waves);
}